// Round 9
// baseline (183.547 us; speedup 1.0000x reference)
//
#include <hip/hip_runtime.h>
#include <hip/hip_bf16.h>

typedef int int4v __attribute__((ext_vector_type(4)));
typedef int int16v __attribute__((ext_vector_type(16)));

#define K_DIM 2048
#define N_DIM 2048
#define M_DIM 16384
#define NW 4194304   // weight element count (2048*2048)
#define BKB 128      // K-step bytes per row (128 i8 elements)
#define NKT (K_DIM / BKB)   // 16 K-tiles

// ---------------- w_scale partials: deterministic f64 ----------------
__global__ void k_wsum(const float4* __restrict__ w4, double* __restrict__ red) {
  const int n4 = NW / 4;
  double s = 0.0;
  for (int i = blockIdx.x * blockDim.x + threadIdx.x; i < n4; i += gridDim.x * blockDim.x) {
    float4 v = w4[i];
    s += (double)fabsf(v.x) + (double)fabsf(v.y) + (double)fabsf(v.z) + (double)fabsf(v.w);
  }
  for (int o = 32; o; o >>= 1) s += __shfl_xor(s, o);
  __shared__ double sd[4];
  if ((threadIdx.x & 63) == 0) sd[threadIdx.x >> 6] = s;
  __syncthreads();
  if (threadIdx.x == 0) red[blockIdx.x] = (sd[0] + sd[1]) + (sd[2] + sd[3]);
}

// ---------------- weight ternary quant (wscale folded in) ----------------
__device__ __forceinline__ char wq1(float v, double ws) {
  double r = rint((double)v / ws);          // round-half-even, matches np.round
  r = fmin(fmax(r, -1.0), 1.0);
  return (char)(int)r;
}

__global__ void k_wquant(const float4* __restrict__ w4, const double* __restrict__ red,
                         double* __restrict__ wsd, char4* __restrict__ wq4) {
  __shared__ double sd[4];
  double s = red[threadIdx.x];
  for (int o = 32; o; o >>= 1) s += __shfl_xor(s, o);
  if ((threadIdx.x & 63) == 0) sd[threadIdx.x >> 6] = s;
  __syncthreads();
  double m = ((sd[0] + sd[1]) + (sd[2] + sd[3])) / (double)NW;
  double ws = (m > 1e-6) ? m : 1e-6;
  if (blockIdx.x == 0 && threadIdx.x == 0) *wsd = ws;   // for k_gemm epilogue
  int i = blockIdx.x * blockDim.x + threadIdx.x;
  if (i >= NW / 4) return;
  float4 v = w4[i];
  char4 q;
  q.x = wq1(v.x, ws);
  q.y = wq1(v.y, ws);
  q.z = wq1(v.z, ws);
  q.w = wq1(v.w, ws);
  wq4[i] = q;
}

// ---------------- per-token absmax + int8 absmax quant ----------------
__device__ __forceinline__ char qi8(float v, double rr) {
  double q = rint((double)v * rr);
  q = fmin(fmax(q, -127.0), 127.0);
  return (char)(int)q;
}

__global__ void k_xquant(const float* __restrict__ x, float* __restrict__ ascale,
                         char* __restrict__ xq) {
  const int row = blockIdx.x;
  const int t = threadIdx.x;
  const float4* xr = (const float4*)(x + (size_t)row * K_DIM);
  float4 v0 = xr[t];
  float4 v1 = xr[t + 256];
  float m = fmaxf(fmaxf(fmaxf(fabsf(v0.x), fabsf(v0.y)), fmaxf(fabsf(v0.z), fabsf(v0.w))),
                  fmaxf(fmaxf(fabsf(v1.x), fabsf(v1.y)), fmaxf(fabsf(v1.z), fabsf(v1.w))));
  for (int o = 32; o; o >>= 1) m = fmaxf(m, __shfl_xor(m, o));
  __shared__ float sm[4];
  if ((t & 63) == 0) sm[t >> 6] = m;
  __syncthreads();
  float a = fmaxf(fmaxf(sm[0], sm[1]), fmaxf(sm[2], sm[3]));
  a = fmaxf(a, 1e-8f);
  if (t == 0) ascale[row] = a;
  double rr = 127.0 / (double)a;
  char4* qr4 = (char4*)(xq + (size_t)row * K_DIM);
  char4 a4, b4;
  a4.x = qi8(v0.x, rr); a4.y = qi8(v0.y, rr); a4.z = qi8(v0.z, rr); a4.w = qi8(v0.w, rr);
  b4.x = qi8(v1.x, rr); b4.y = qi8(v1.y, rr); b4.z = qi8(v1.z, rr); b4.w = qi8(v1.w, rr);
  qr4[t] = a4;
  qr4[t + 256] = b4;
}

// ---------------- GEMM: 256x256, 4 fat waves (128x128 each), 32x32x32 i8 -----
__device__ __forceinline__ void gload16(const void* g, void* l) {
  __builtin_amdgcn_global_load_lds(
      (const __attribute__((address_space(1))) void*)g,
      (__attribute__((address_space(3))) void*)l, 16, 0, 0);
}

#define RD_A(DST, CA, KS)                                                   \
  _Pragma("unroll") for (int mf = 0; mf < 4; ++mf)                          \
    DST[mf] = *(const int4v*)((CA) + (rA + mf * 32) * 128 + co[KS]);

#define RD_B(DST, CB, KS)                                                   \
  _Pragma("unroll") for (int nf = 0; nf < 4; ++nf)                          \
    DST[nf] = *(const int4v*)((CB) + (rB + nf * 32) * 128 + co[KS]);

#define MM(AF, BF)                                                          \
  _Pragma("unroll") for (int mf = 0; mf < 4; ++mf)                          \
  _Pragma("unroll") for (int nf = 0; nf < 4; ++nf)                          \
    acc[mf][nf] = __builtin_amdgcn_mfma_i32_32x32x32_i8(                    \
        AF[mf], BF[nf], acc[mf][nf], 0, 0, 0);

// One K-tile: stage next tile early (long flight), per-ks frag reads issued
// one step ahead of their MFMA cluster (in-order issue => LDS service of
// ks+1 overlaps the 586-cy MFMA cluster of ks). One vmcnt gate + one barrier.
#define TILE(CA, CB, NA, NB, KT)                                            \
  {                                                                         \
    const char* An = Ab + (((KT) + 1) & (NKT - 1)) * BKB;                   \
    const char* Bn = Bb + (((KT) + 1) & (NKT - 1)) * BKB;                   \
    RD_A(aX, CA, 0);                                                        \
    RD_B(bX, CB, 0);                                                        \
    _Pragma("unroll") for (int c = 0; c < 8; ++c)                           \
      gload16(An + soff[c], (NA) + loff[c]);                                \
    RD_A(aY, CA, 1);                                                        \
    RD_B(bY, CB, 1);                                                        \
    _Pragma("unroll") for (int c = 0; c < 8; ++c)                           \
      gload16(Bn + soff[c], (NB) + loff[c]);                                \
    MM(aX, bX);                                                             \
    RD_A(aX, CA, 2);                                                        \
    RD_B(bX, CB, 2);                                                        \
    MM(aY, bY);                                                             \
    RD_A(aY, CA, 3);                                                        \
    RD_B(bY, CB, 3);                                                        \
    MM(aX, bX);                                                             \
    MM(aY, bY);                                                             \
    asm volatile("s_waitcnt vmcnt(0)" ::: "memory");                        \
    __builtin_amdgcn_s_barrier();                                           \
  }

__global__ __launch_bounds__(256, 1) void k_gemm(
    const char* __restrict__ xq, const char* __restrict__ wq,
    const float* __restrict__ ascale, const double* __restrict__ wsd,
    float* __restrict__ out) {
  __shared__ __align__(16) char lds[131072];
  char* A0 = lds;            // 32 KB
  char* B0 = lds + 32768;
  char* A1 = lds + 65536;
  char* B1 = lds + 98304;

  const int tid = threadIdx.x;
  const int l = tid & 63;
  const int wv = tid >> 6;        // 0..3
  const int wm = wv >> 1;         // M half
  const int wn = wv & 1;          // N half
  const int r32 = l & 31;
  const int hk = (l >> 5) * 16;   // K-half byte offset within 32B k-slice

  // XCD-aware bijective swizzle: 512 blocks = 8 xcd * 64 chunk
  const int bid = blockIdx.x;
  const int logical = (bid & 7) * 64 + (bid >> 3);
  const int br = logical >> 3;    // 0..63  (M blocks)
  const int bc = logical & 7;     // 0..7   (N blocks)

  const char* Ab = xq + (size_t)br * 256 * K_DIM;
  const char* Bb = wq + (size_t)bc * 256 * K_DIM;

  // staging: LDS dest linear (global_load_lds constraint), source pre-swizzled.
  // operand tile = 256 rows x 128 B = 32 KB = 8 chunks of 4 KB (8 loads/thread)
  int soff[8], loff[8];
#pragma unroll
  for (int c = 0; c < 8; ++c) {
    int lb = c * 4096 + tid * 16;
    loff[c] = lb;
    int row = lb >> 7;
    int cb = lb & 127;
    soff[c] = row * K_DIM + (cb ^ ((row & 7) << 4));
  }

  // read-side swizzled k-offsets; frag rows have (row&7) == (l&7)
  const int sw = (l & 7) << 4;
  int co[4];
#pragma unroll
  for (int k = 0; k < 4; ++k) co[k] = (k * 32 + hk) ^ sw;
  const int rA = wm * 128 + r32;
  const int rB = wn * 128 + r32;

  int16v acc[4][4];
#pragma unroll
  for (int mf = 0; mf < 4; ++mf)
#pragma unroll
    for (int nf = 0; nf < 4; ++nf)
#pragma unroll
      for (int j = 0; j < 16; ++j) acc[mf][nf][j] = 0;

  // prologue: stage tile 0 into buf0, drain, sync
#pragma unroll
  for (int c = 0; c < 8; ++c) gload16(Ab + soff[c], A0 + loff[c]);
#pragma unroll
  for (int c = 0; c < 8; ++c) gload16(Bb + soff[c], B0 + loff[c]);
  asm volatile("s_waitcnt vmcnt(0)" ::: "memory");
  __builtin_amdgcn_s_barrier();

  int4v aX[4], aY[4], bX[4], bY[4];

  for (int kt = 0; kt < NKT; kt += 2) {
    TILE(A0, B0, A1, B1, kt);
    TILE(A1, B1, A0, B0, kt + 1);
  }

  // epilogue: y = acc * w_scale * (a_scale[t]/127); |acc| <= 127*2048 < 2^24 exact
  // 32x32 C/D layout: col = lane&31, row = (reg&3) + 8*(reg>>2) + 4*(lane>>5)
  float wsf = (float)(*wsd);
  size_t r0 = (size_t)br * 256 + wm * 128;
  int c0 = bc * 256 + wn * 128;
#pragma unroll
  for (int mf = 0; mf < 4; ++mf) {
#pragma unroll
    for (int j = 0; j < 16; ++j) {
      size_t row = r0 + mf * 32 + (j & 3) + 8 * (j >> 2) + 4 * (l >> 5);
      float s = wsf * (ascale[row] / 127.0f);
      float* yr = out + row * (size_t)N_DIM + c0;
#pragma unroll
      for (int nf = 0; nf < 4; ++nf)
        yr[nf * 32 + r32] = (float)acc[mf][nf][j] * s;
    }
  }
}

extern "C" void kernel_launch(void* const* d_in, const int* in_sizes, int n_in,
                              void* d_out, int out_size, void* d_ws, size_t ws_size,
                              hipStream_t stream) {
  const float* x = (const float*)d_in[0];
  const float* w = (const float*)d_in[1];
  float* out = (float*)d_out;

  char* ws = (char*)d_ws;
  double* red = (double*)ws;                               // 256 * 8 B
  double* wsd = (double*)(ws + 2048);                      // 1 double
  float* ascale = (float*)(ws + 4096);                     // 16384 floats
  char* xq = (char*)(ws + 4096 + 65536);                   // 32 MiB
  char* wq = xq + (size_t)M_DIM * K_DIM;                   // 4 MiB

  k_wsum<<<256, 256, 0, stream>>>((const float4*)w, red);
  k_wquant<<<NW / 4 / 256, 256, 0, stream>>>((const float4*)w, red, wsd, (char4*)wq);
  k_xquant<<<M_DIM, 256, 0, stream>>>(x, ascale, xq);
  k_gemm<<<dim3(N_DIM / 256 * M_DIM / 256), 256, 0, stream>>>(xq, wq, ascale, wsd, out);
}

// Round 10
// 131.714 us; speedup vs baseline: 1.3935x; 1.3935x over previous
//
#include <hip/hip_runtime.h>
#include <hip/hip_bf16.h>

typedef int int4v __attribute__((ext_vector_type(4)));

#define K_DIM 2048
#define N_DIM 2048
#define M_DIM 16384
#define NW 4194304   // weight element count (2048*2048)
#define BKB 128      // K-step bytes per row (128 i8 elements)
#define NKT (K_DIM / BKB)   // 16 K-tiles

// ---------------- w_scale partials: deterministic f64 ----------------
__global__ void k_wsum(const float4* __restrict__ w4, double* __restrict__ red) {
  const int n4 = NW / 4;
  double s = 0.0;
  for (int i = blockIdx.x * blockDim.x + threadIdx.x; i < n4; i += gridDim.x * blockDim.x) {
    float4 v = w4[i];
    s += (double)fabsf(v.x) + (double)fabsf(v.y) + (double)fabsf(v.z) + (double)fabsf(v.w);
  }
  for (int o = 32; o; o >>= 1) s += __shfl_xor(s, o);
  __shared__ double sd[4];
  if ((threadIdx.x & 63) == 0) sd[threadIdx.x >> 6] = s;
  __syncthreads();
  if (threadIdx.x == 0) red[blockIdx.x] = (sd[0] + sd[1]) + (sd[2] + sd[3]);
}

// ---------------- weight ternary quant (wscale folded in) ----------------
__device__ __forceinline__ char wq1(float v, double ws) {
  double r = rint((double)v / ws);          // round-half-even, matches np.round
  r = fmin(fmax(r, -1.0), 1.0);
  return (char)(int)r;
}

__global__ void k_wquant(const float4* __restrict__ w4, const double* __restrict__ red,
                         double* __restrict__ wsd, char4* __restrict__ wq4) {
  __shared__ double sd[4];
  double s = red[threadIdx.x];
  for (int o = 32; o; o >>= 1) s += __shfl_xor(s, o);
  if ((threadIdx.x & 63) == 0) sd[threadIdx.x >> 6] = s;
  __syncthreads();
  double m = ((sd[0] + sd[1]) + (sd[2] + sd[3])) / (double)NW;
  double ws = (m > 1e-6) ? m : 1e-6;
  if (blockIdx.x == 0 && threadIdx.x == 0) *wsd = ws;   // for k_gemm epilogue
  int i = blockIdx.x * blockDim.x + threadIdx.x;
  if (i >= NW / 4) return;
  float4 v = w4[i];
  char4 q;
  q.x = wq1(v.x, ws);
  q.y = wq1(v.y, ws);
  q.z = wq1(v.z, ws);
  q.w = wq1(v.w, ws);
  wq4[i] = q;
}

// ---------------- per-token absmax + int8 absmax quant ----------------
__device__ __forceinline__ char qi8(float v, double rr) {
  double q = rint((double)v * rr);
  q = fmin(fmax(q, -127.0), 127.0);
  return (char)(int)q;
}

__global__ void k_xquant(const float* __restrict__ x, float* __restrict__ ascale,
                         char* __restrict__ xq) {
  const int row = blockIdx.x;
  const int t = threadIdx.x;
  const float4* xr = (const float4*)(x + (size_t)row * K_DIM);
  float4 v0 = xr[t];
  float4 v1 = xr[t + 256];
  float m = fmaxf(fmaxf(fmaxf(fabsf(v0.x), fabsf(v0.y)), fmaxf(fabsf(v0.z), fabsf(v0.w))),
                  fmaxf(fmaxf(fabsf(v1.x), fabsf(v1.y)), fmaxf(fabsf(v1.z), fabsf(v1.w))));
  for (int o = 32; o; o >>= 1) m = fmaxf(m, __shfl_xor(m, o));
  __shared__ float sm[4];
  if ((t & 63) == 0) sm[t >> 6] = m;
  __syncthreads();
  float a = fmaxf(fmaxf(sm[0], sm[1]), fmaxf(sm[2], sm[3]));
  a = fmaxf(a, 1e-8f);
  if (t == 0) ascale[row] = a;
  double rr = 127.0 / (double)a;
  char4* qr4 = (char4*)(xq + (size_t)row * K_DIM);
  char4 a4, b4;
  a4.x = qi8(v0.x, rr); a4.y = qi8(v0.y, rr); a4.z = qi8(v0.z, rr); a4.w = qi8(v0.w, rr);
  b4.x = qi8(v1.x, rr); b4.y = qi8(v1.y, rr); b4.z = qi8(v1.z, rr); b4.w = qi8(v1.w, rr);
  qr4[t] = a4;
  qr4[t + 256] = b4;
}

// ------- GEMM: 128x128 tile, 4 waves, 2 blocks/CU, deep-staged dbuf ---------
__device__ __forceinline__ void gload16(const void* g, void* l) {
  __builtin_amdgcn_global_load_lds(
      (const __attribute__((address_space(1))) void*)g,
      (__attribute__((address_space(3))) void*)l, 16, 0, 0);
}

#define RD_A(DST, CA, CO)                                                   \
  _Pragma("unroll") for (int mf = 0; mf < 4; ++mf)                          \
    DST[mf] = *(const int4v*)((CA) + (rA + mf * 16) * 128 + (CO));

#define RD_B(DST, CB, CO)                                                   \
  _Pragma("unroll") for (int nf = 0; nf < 4; ++nf)                          \
    DST[nf] = *(const int4v*)((CB) + (rB + nf * 16) * 128 + (CO));

#define MM(AF, BF)                                                          \
  _Pragma("unroll") for (int mf = 0; mf < 4; ++mf)                          \
  _Pragma("unroll") for (int nf = 0; nf < 4; ++nf)                          \
    acc[mf][nf] = __builtin_amdgcn_mfma_i32_16x16x64_i8(                    \
        AF[mf], BF[nf], acc[mf][nf], 0, 0, 0);

// One K-tile, no mid-tile barriers:
//  - stage next tile FIRST (max flight; gated only at tile end ~900cy later)
//  - read ALL 16 frags up-front into 4 reg sets (ks1 reads fly during ks0 MFMA)
//  - 2 MFMA clusters; compiler emits counted lgkm waits
//  - one vmcnt(0)+barrier at tile end (stage landed + all reads of cbuf done)
#define KTILE(CBUF, NBUF, KT)                                               \
  {                                                                         \
    const char* An = Ab + (((KT) + 1) & (NKT - 1)) * BKB;                   \
    const char* Bn = Bb + (((KT) + 1) & (NKT - 1)) * BKB;                   \
    _Pragma("unroll") for (int c = 0; c < 4; ++c)                           \
      gload16(An + soff[c], (NBUF) + loff[c]);                              \
    _Pragma("unroll") for (int c = 0; c < 4; ++c)                           \
      gload16(Bn + soff[c], (NBUF) + 16384 + loff[c]);                      \
    RD_A(a0, CBUF, co0);                                                    \
    RD_B(b0, (CBUF) + 16384, co0);                                          \
    RD_A(a1, CBUF, co1);                                                    \
    RD_B(b1, (CBUF) + 16384, co1);                                          \
    MM(a0, b0);                                                             \
    MM(a1, b1);                                                             \
    asm volatile("s_waitcnt vmcnt(0)" ::: "memory");                        \
    __builtin_amdgcn_s_barrier();                                           \
  }

__global__ __launch_bounds__(256) void k_gemm(
    const char* __restrict__ xq, const char* __restrict__ wq,
    const float* __restrict__ ascale, const double* __restrict__ wsd,
    float* __restrict__ out) {
  __shared__ __align__(16) char lds[65536];   // 2 bufs x (A 16K | B 16K)
  char* buf0 = lds;
  char* buf1 = lds + 32768;

  const int tid = threadIdx.x;
  const int l = tid & 63;
  const int wv = tid >> 6;        // 0..3
  const int wm = wv >> 1;         // M half of 128
  const int wn = wv & 1;          // N half of 128
  const int g = l >> 4, r16 = l & 15;

  // XCD bijective swizzle: 2048 blocks = 8 xcd * 256; each XCD gets 16 M-rows
  // x 16 N-cols of tiles (A/B panels ~4 MB each -> L2-resident per XCD)
  const int bid = blockIdx.x;
  const int logical = (bid & 7) * 256 + (bid >> 3);
  const int br = logical >> 4;    // 0..127 (M blocks)
  const int bc = logical & 15;    // 0..15  (N blocks)

  const char* Ab = xq + (size_t)br * 128 * K_DIM;
  const char* Bb = wq + (size_t)bc * 128 * K_DIM;

  // staging: LDS dest linear (global_load_lds constraint), source pre-swizzled.
  // operand tile = 128 rows x 128 B = 16 KB = 4 chunks of 4 KB (256 thr x 16 B)
  int soff[4], loff[4];
#pragma unroll
  for (int c = 0; c < 4; ++c) {
    int lb = c * 4096 + tid * 16;
    loff[c] = lb;
    int row = lb >> 7;
    int cb = lb & 127;
    soff[c] = row * K_DIM + (cb ^ ((row & 7) << 4));
  }

  // read-side swizzled column offsets (row&7 == r16&7 for all fragment rows)
  const int sw = (r16 & 7) << 4;
  const int co0 = (g * 16) ^ sw;        // k-slice 0
  const int co1 = (64 + g * 16) ^ sw;   // k-slice 1
  const int rA = wm * 64 + r16;
  const int rB = wn * 64 + r16;

  int4v acc[4][4];
#pragma unroll
  for (int mf = 0; mf < 4; ++mf)
#pragma unroll
    for (int nf = 0; nf < 4; ++nf) acc[mf][nf] = (int4v){0, 0, 0, 0};

  // prologue: stage tile 0 into buf0, drain, sync
#pragma unroll
  for (int c = 0; c < 4; ++c) gload16(Ab + soff[c], buf0 + loff[c]);
#pragma unroll
  for (int c = 0; c < 4; ++c) gload16(Bb + soff[c], buf0 + 16384 + loff[c]);
  asm volatile("s_waitcnt vmcnt(0)" ::: "memory");
  __builtin_amdgcn_s_barrier();

  int4v a0[4], a1[4], b0[4], b1[4];

  for (int kt = 0; kt < NKT; kt += 2) {
    KTILE(buf0, buf1, kt);
    KTILE(buf1, buf0, kt + 1);
  }

  // epilogue: y = acc * w_scale * (a_scale[t]/127); |acc| <= 127*2048 < 2^24 exact
  float wsf = (float)(*wsd);
  size_t trow0 = (size_t)br * 128 + wm * 64;
  int oc0 = bc * 128 + wn * 64;
#pragma unroll
  for (int mf = 0; mf < 4; ++mf) {
#pragma unroll
    for (int j = 0; j < 4; ++j) {
      size_t t = trow0 + mf * 16 + g * 4 + j;  // C/D: col=lane&15, row=(lane>>4)*4+reg
      float s = wsf * (ascale[t] / 127.0f);
      float* yr = out + t * (size_t)N_DIM + oc0;
#pragma unroll
      for (int nf = 0; nf < 4; ++nf) yr[nf * 16 + r16] = (float)acc[mf][nf][j] * s;
    }
  }
}

extern "C" void kernel_launch(void* const* d_in, const int* in_sizes, int n_in,
                              void* d_out, int out_size, void* d_ws, size_t ws_size,
                              hipStream_t stream) {
  const float* x = (const float*)d_in[0];
  const float* w = (const float*)d_in[1];
  float* out = (float*)d_out;

  char* ws = (char*)d_ws;
  double* red = (double*)ws;                               // 256 * 8 B
  double* wsd = (double*)(ws + 2048);                      // 1 double
  float* ascale = (float*)(ws + 4096);                     // 16384 floats
  char* xq = (char*)(ws + 4096 + 65536);                   // 32 MiB
  char* wq = xq + (size_t)M_DIM * K_DIM;                   // 4 MiB

  k_wsum<<<256, 256, 0, stream>>>((const float4*)w, red);
  k_wquant<<<NW / 4 / 256, 256, 0, stream>>>((const float4*)w, red, wsd, (char4*)wq);
  k_xquant<<<M_DIM, 256, 0, stream>>>(x, ascale, xq);
  k_gemm<<<dim3((M_DIM / 128) * (N_DIM / 128)), 256, 0, stream>>>(xq, wq, ascale, wsd, out);
}

// Round 11
// 122.466 us; speedup vs baseline: 1.4988x; 1.0755x over previous
//
#include <hip/hip_runtime.h>
#include <hip/hip_bf16.h>

typedef int int4v __attribute__((ext_vector_type(4)));

#define K_DIM 2048
#define N_DIM 2048
#define M_DIM 16384
#define NW 4194304   // weight element count (2048*2048)
#define BKB 64       // K-step bytes per row (64 i8 elements)
#define NKT 32       // K-tiles

// ------------- fused: per-token absmax+quant, plus wsum slice (blocks<256) ---
__device__ __forceinline__ char qi8(float v, double rr) {
  double q = rint((double)v * rr);
  q = fmin(fmax(q, -127.0), 127.0);
  return (char)(int)q;
}

__global__ void k_xquant(const float* __restrict__ x, float* __restrict__ ascale,
                         char* __restrict__ xq, const float4* __restrict__ w4,
                         double* __restrict__ red) {
  const int row = blockIdx.x;
  const int t = threadIdx.x;
  const float4* xr = (const float4*)(x + (size_t)row * K_DIM);
  float4 v0 = xr[t];
  float4 v1 = xr[t + 256];
  float m = fmaxf(fmaxf(fmaxf(fabsf(v0.x), fabsf(v0.y)), fmaxf(fabsf(v0.z), fabsf(v0.w))),
                  fmaxf(fmaxf(fabsf(v1.x), fabsf(v1.y)), fmaxf(fabsf(v1.z), fabsf(v1.w))));
  for (int o = 32; o; o >>= 1) m = fmaxf(m, __shfl_xor(m, o));
  __shared__ float sm[4];
  if ((t & 63) == 0) sm[t >> 6] = m;
  __syncthreads();
  float a = fmaxf(fmaxf(sm[0], sm[1]), fmaxf(sm[2], sm[3]));
  a = fmaxf(a, 1e-8f);
  if (t == 0) ascale[row] = a;
  double rr = 127.0 / (double)a;
  char4* qr4 = (char4*)(xq + (size_t)row * K_DIM);
  char4 a4, b4;
  a4.x = qi8(v0.x, rr); a4.y = qi8(v0.y, rr); a4.z = qi8(v0.z, rr); a4.w = qi8(v0.w, rr);
  b4.x = qi8(v1.x, rr); b4.y = qi8(v1.y, rr); b4.z = qi8(v1.z, rr); b4.w = qi8(v1.w, rr);
  qr4[t] = a4;
  qr4[t + 256] = b4;

  // fused w abs-sum (deterministic partials), blocks 0..255 only
  if (row < 256) {
    const int n4 = NW / 4;
    double s = 0.0;
    for (int i = row * 256 + t; i < n4; i += 256 * 256) {
      float4 v = w4[i];
      s += (double)fabsf(v.x) + (double)fabsf(v.y) + (double)fabsf(v.z) + (double)fabsf(v.w);
    }
    for (int o = 32; o; o >>= 1) s += __shfl_xor(s, o);
    __shared__ double sd[4];
    if ((t & 63) == 0) sd[t >> 6] = s;
    __syncthreads();
    if (t == 0) red[row] = (sd[0] + sd[1]) + (sd[2] + sd[3]);
  }
}

// ---------------- weight ternary quant (wscale folded in) ----------------
__device__ __forceinline__ char wq1(float v, double ws) {
  double r = rint((double)v / ws);          // round-half-even, matches np.round
  r = fmin(fmax(r, -1.0), 1.0);
  return (char)(int)r;
}

__global__ void k_wquant(const float4* __restrict__ w4, const double* __restrict__ red,
                         double* __restrict__ wsd, char4* __restrict__ wq4) {
  __shared__ double sd[4];
  double s = red[threadIdx.x];
  for (int o = 32; o; o >>= 1) s += __shfl_xor(s, o);
  if ((threadIdx.x & 63) == 0) sd[threadIdx.x >> 6] = s;
  __syncthreads();
  double m = ((sd[0] + sd[1]) + (sd[2] + sd[3])) / (double)NW;
  double ws = (m > 1e-6) ? m : 1e-6;
  if (blockIdx.x == 0 && threadIdx.x == 0) *wsd = ws;   // for k_gemm epilogue
  int i = blockIdx.x * blockDim.x + threadIdx.x;
  if (i >= NW / 4) return;
  float4 v = w4[i];
  char4 q;
  q.x = wq1(v.x, ws);
  q.y = wq1(v.y, ws);
  q.z = wq1(v.z, ws);
  q.w = wq1(v.w, ws);
  wq4[i] = q;
}

// --- GEMM: 256x256, 8 waves, BK=64, 4-buffer LDS, 2-tile-deep staging --------
__device__ __forceinline__ void gload16(const void* g, void* l) {
  __builtin_amdgcn_global_load_lds(
      (const __attribute__((address_space(1))) void*)g,
      (__attribute__((address_space(3))) void*)l, 16, 0, 0);
}

#define RD_A(DST, CA, MH)                                                   \
  _Pragma("unroll") for (int mf = 0; mf < 4; ++mf)                          \
    DST[mf] = *(const int4v*)((CA) + (rA + (MH)*64 + mf * 16) * 64 + co);

#define RD_B(DST, CB)                                                       \
  _Pragma("unroll") for (int nf = 0; nf < 4; ++nf)                          \
    DST[nf] = *(const int4v*)((CB) + (rB + nf * 16) * 64 + co);

#define MM(MH, AF, BF)                                                      \
  __builtin_amdgcn_s_setprio(1);                                            \
  _Pragma("unroll") for (int mf = 0; mf < 4; ++mf)                          \
  _Pragma("unroll") for (int nf = 0; nf < 4; ++nf)                          \
    acc[(MH)*4 + mf][nf] = __builtin_amdgcn_mfma_i32_16x16x64_i8(           \
        AF[mf], BF[nf], acc[(MH)*4 + mf][nf], 0, 0, 0);                     \
  __builtin_amdgcn_s_setprio(0);

#define SBAR __builtin_amdgcn_s_barrier()
#define VM4  asm volatile("s_waitcnt vmcnt(4)" ::: "memory")

// One K-tile = 2 phases, ONE barrier per phase (between reads and MFMA).
// Staging TWO tiles ahead (t kt+2 -> buf[(kt+2)&3]); flight ~2 tiles => the
// tile-end vmcnt(4) (retire all but t(kt+2)'s 4) is free. No post-MFMA
// barrier: waves run ahead into next phase's reads while the pipe drains.
#define TILE64(CI, SI, KT)                                                  \
  {                                                                         \
    const char* cb_ = lds + (CI)*32768;                                     \
    char* sb_ = lds + (SI)*32768;                                           \
    const int kk = ((KT) + 2) & (NKT - 1);                                  \
    /* ph0: 8 reads | BAR | stage A(kt+2) | 16 MFMA */                      \
    RD_B(bf, cb_ + 16384);                                                  \
    RD_A(af, cb_, 0);                                                       \
    SBAR;                                                                   \
    gload16(Ab + kk * BKB + soff[0], sb_ + loff[0]);                        \
    gload16(Ab + kk * BKB + soff[1], sb_ + loff[1]);                        \
    MM(0, af, bf);                                                          \
    /* ph1: 4 reads | BAR | stage B(kt+2) | 16 MFMA | gate+BAR */           \
    RD_A(af2, cb_, 1);                                                      \
    SBAR;                                                                   \
    gload16(Bb + kk * BKB + soff[0], sb_ + 16384 + loff[0]);                \
    gload16(Bb + kk * BKB + soff[1], sb_ + 16384 + loff[1]);                \
    MM(1, af2, bf);                                                         \
    VM4;                                                                    \
    SBAR;                                                                   \
  }

__global__ __launch_bounds__(512, 1) void k_gemm(
    const char* __restrict__ xq, const char* __restrict__ wq,
    const float* __restrict__ ascale, const double* __restrict__ wsd,
    float* __restrict__ out) {
  __shared__ __align__(16) char lds[131072];   // 4 bufs x (A 16K | B 16K)

  const int tid = threadIdx.x;
  const int l = tid & 63;
  const int wv = tid >> 6;        // 0..7
  const int wm = wv >> 2;         // M half
  const int wn = wv & 3;          // N quarter
  const int g = l >> 4, r16 = l & 15;

  // XCD-aware bijective swizzle: 512 blocks = 8 xcd * 64 chunk
  const int bid = blockIdx.x;
  const int logical = (bid & 7) * 64 + (bid >> 3);
  const int br = logical >> 3;    // 0..63  (M blocks)
  const int bc = logical & 7;     // 0..7   (N blocks)

  const char* Ab = xq + (size_t)br * 256 * K_DIM;
  const char* Bb = wq + (size_t)bc * 256 * K_DIM;

  // staging: operand tile = 256 rows x 64 B = 16 KB = 2 chunks (512 thr x 16 B)
  // LDS dest linear (global_load_lds constraint), source pre-swizzled with the
  // involution byte ^= (row&3)<<4 (64 B rows; read-side uses the same XOR).
  int soff[2], loff[2];
#pragma unroll
  for (int c = 0; c < 2; ++c) {
    int lb = c * 8192 + tid * 16;
    loff[c] = lb;
    int row = lb >> 6;
    int cb = lb & 63;
    soff[c] = row * K_DIM + (cb ^ ((row & 3) << 4));
  }

  // read-side swizzled k-offset; frag rows all have (row&3) == (r16&3)
  const int co = (g * 16) ^ ((r16 & 3) << 4);
  const int rA = wm * 128 + r16;
  const int rB = wn * 64 + r16;

  int4v acc[8][4];
#pragma unroll
  for (int mf = 0; mf < 8; ++mf)
#pragma unroll
    for (int nf = 0; nf < 4; ++nf) acc[mf][nf] = (int4v){0, 0, 0, 0};

  // prologue: stage t0 -> buf0, t1 -> buf1; wait t0 (vmcnt(4)); sync
#pragma unroll
  for (int c = 0; c < 2; ++c) {
    gload16(Ab + soff[c], lds + loff[c]);
    gload16(Bb + soff[c], lds + 16384 + loff[c]);
  }
#pragma unroll
  for (int c = 0; c < 2; ++c) {
    gload16(Ab + BKB + soff[c], lds + 32768 + loff[c]);
    gload16(Bb + BKB + soff[c], lds + 32768 + 16384 + loff[c]);
  }
  VM4;
  SBAR;

  int4v af[4], af2[4], bf[4];

  for (int kt = 0; kt < NKT; kt += 4) {
    TILE64(0, 2, kt);
    TILE64(1, 3, kt + 1);
    TILE64(2, 0, kt + 2);
    TILE64(3, 1, kt + 3);
  }

  // epilogue: y = acc * w_scale * (a_scale[t]/127); |acc| <= 127*2048 < 2^24 exact
  float wsf = (float)(*wsd);
  size_t trow0 = (size_t)br * 256 + wm * 128;
  int oc0 = bc * 256 + wn * 64;
#pragma unroll
  for (int mf = 0; mf < 8; ++mf) {
#pragma unroll
    for (int j = 0; j < 4; ++j) {
      size_t t = trow0 + mf * 16 + g * 4 + j;  // C/D: col=lane&15, row=(lane>>4)*4+reg
      float s = wsf * (ascale[t] / 127.0f);
      float* yr = out + t * (size_t)N_DIM + oc0;
#pragma unroll
      for (int nf = 0; nf < 4; ++nf) yr[nf * 16 + r16] = (float)acc[mf][nf][j] * s;
    }
  }
}

extern "C" void kernel_launch(void* const* d_in, const int* in_sizes, int n_in,
                              void* d_out, int out_size, void* d_ws, size_t ws_size,
                              hipStream_t stream) {
  const float* x = (const float*)d_in[0];
  const float* w = (const float*)d_in[1];
  float* out = (float*)d_out;

  char* ws = (char*)d_ws;
  double* red = (double*)ws;                               // 256 * 8 B
  double* wsd = (double*)(ws + 2048);                      // 1 double
  float* ascale = (float*)(ws + 4096);                     // 16384 floats
  char* xq = (char*)(ws + 4096 + 65536);                   // 32 MiB
  char* wq = xq + (size_t)M_DIM * K_DIM;                   // 4 MiB

  k_xquant<<<M_DIM, 256, 0, stream>>>(x, ascale, xq, (const float4*)w, red);
  k_wquant<<<NW / 4 / 256, 256, 0, stream>>>((const float4*)w, red, wsd, (char4*)wq);
  k_gemm<<<dim3(N_DIM / 256 * M_DIM / 256), 512, 0, stream>>>(xq, wq, ascale, wsd, out);
}

// Round 12
// 115.597 us; speedup vs baseline: 1.5878x; 1.0594x over previous
//
#include <hip/hip_runtime.h>
#include <hip/hip_bf16.h>

typedef int int4v __attribute__((ext_vector_type(4)));

#define K_DIM 2048
#define N_DIM 2048
#define M_DIM 16384
#define NW 4194304   // weight element count (2048*2048)
#define BKB 128      // K-step bytes per row (128 i8 elements)
#define NKT (K_DIM / BKB)   // 16 K-tiles

// ------------- fused: per-token absmax+quant, plus wsum slice (blocks<256) ---
__device__ __forceinline__ char qi8(float v, double rr) {
  double q = rint((double)v * rr);
  q = fmin(fmax(q, -127.0), 127.0);
  return (char)(int)q;
}

__global__ void k_xquant(const float* __restrict__ x, float* __restrict__ ascale,
                         char* __restrict__ xq, const float4* __restrict__ w4,
                         double* __restrict__ red) {
  const int row = blockIdx.x;
  const int t = threadIdx.x;
  const float4* xr = (const float4*)(x + (size_t)row * K_DIM);
  float4 v0 = xr[t];
  float4 v1 = xr[t + 256];
  float m = fmaxf(fmaxf(fmaxf(fabsf(v0.x), fabsf(v0.y)), fmaxf(fabsf(v0.z), fabsf(v0.w))),
                  fmaxf(fmaxf(fabsf(v1.x), fabsf(v1.y)), fmaxf(fabsf(v1.z), fabsf(v1.w))));
  for (int o = 32; o; o >>= 1) m = fmaxf(m, __shfl_xor(m, o));
  __shared__ float sm[4];
  if ((t & 63) == 0) sm[t >> 6] = m;
  __syncthreads();
  float a = fmaxf(fmaxf(sm[0], sm[1]), fmaxf(sm[2], sm[3]));
  a = fmaxf(a, 1e-8f);
  if (t == 0) ascale[row] = a;
  double rr = 127.0 / (double)a;
  char4* qr4 = (char4*)(xq + (size_t)row * K_DIM);
  char4 a4, b4;
  a4.x = qi8(v0.x, rr); a4.y = qi8(v0.y, rr); a4.z = qi8(v0.z, rr); a4.w = qi8(v0.w, rr);
  b4.x = qi8(v1.x, rr); b4.y = qi8(v1.y, rr); b4.z = qi8(v1.z, rr); b4.w = qi8(v1.w, rr);
  qr4[t] = a4;
  qr4[t + 256] = b4;

  // fused w abs-sum (deterministic partials), blocks 0..255 only
  if (row < 256) {
    const int n4 = NW / 4;
    double s = 0.0;
    for (int i = row * 256 + t; i < n4; i += 256 * 256) {
      float4 v = w4[i];
      s += (double)fabsf(v.x) + (double)fabsf(v.y) + (double)fabsf(v.z) + (double)fabsf(v.w);
    }
    for (int o = 32; o; o >>= 1) s += __shfl_xor(s, o);
    __shared__ double sd[4];
    if ((t & 63) == 0) sd[t >> 6] = s;
    __syncthreads();
    if (t == 0) red[row] = (sd[0] + sd[1]) + (sd[2] + sd[3]);
  }
}

// ---------------- weight ternary quant (wscale folded in) ----------------
__device__ __forceinline__ char wq1(float v, double inv) {
  double r = rint((double)v * inv);         // f64 mul: <=1ulp vs divide, safe
  r = fmin(fmax(r, -1.0), 1.0);
  return (char)(int)r;
}

__global__ void k_wquant(const float4* __restrict__ w4, const double* __restrict__ red,
                         double* __restrict__ wsd, char4* __restrict__ wq4) {
  __shared__ double sd[4];
  double s = red[threadIdx.x];
  for (int o = 32; o; o >>= 1) s += __shfl_xor(s, o);
  if ((threadIdx.x & 63) == 0) sd[threadIdx.x >> 6] = s;
  __syncthreads();
  double m = ((sd[0] + sd[1]) + (sd[2] + sd[3])) / (double)NW;
  double ws = (m > 1e-6) ? m : 1e-6;
  if (blockIdx.x == 0 && threadIdx.x == 0) *wsd = ws;   // for k_gemm epilogue
  double inv = 1.0 / ws;
  int i = blockIdx.x * blockDim.x + threadIdx.x;
  if (i >= NW / 4) return;
  float4 v = w4[i];
  char4 q;
  q.x = wq1(v.x, inv);
  q.y = wq1(v.y, inv);
  q.z = wq1(v.z, inv);
  q.w = wq1(v.w, inv);
  wq4[i] = q;
}

// --- GEMM: 256x256, 8 waves, BK=128, ONE barrier per ktile (free-run) --------
__device__ __forceinline__ void gload16(const void* g, void* l) {
  __builtin_amdgcn_global_load_lds(
      (const __attribute__((address_space(1))) void*)g,
      (__attribute__((address_space(3))) void*)l, 16, 0, 0);
}

#define RD_A(DST, CA, MH, CO)                                               \
  _Pragma("unroll") for (int mf = 0; mf < 4; ++mf)                          \
    DST[mf] = *(const int4v*)((CA) + (rA + (MH)*64 + mf * 16) * 128 + (CO));

#define RD_B(DST, CB, CO)                                                   \
  _Pragma("unroll") for (int nf = 0; nf < 4; ++nf)                          \
    DST[nf] = *(const int4v*)((CB) + (rB + nf * 16) * 128 + (CO));

#define MM(MH, AF, BF)                                                      \
  __builtin_amdgcn_s_setprio(1);                                            \
  _Pragma("unroll") for (int mf = 0; mf < 4; ++mf)                          \
  _Pragma("unroll") for (int nf = 0; nf < 4; ++nf)                          \
    acc[(MH)*4 + mf][nf] = __builtin_amdgcn_mfma_i32_16x16x64_i8(           \
        AF[mf], BF[nf], acc[(MH)*4 + mf][nf], 0, 0, 0);                     \
  __builtin_amdgcn_s_setprio(0);

// One K-tile, NO mid-tile barriers (R9 discipline at R6 geometry):
//  - stage next tile at top (flight = full ktile >> L2 latency)
//  - frag reads interleaved between MFMA clusters; compiler emits counted
//    lgkm waits per cluster; the 2 waves/SIMD desync and overlap naturally
//  - one vmcnt(0)+barrier at tile end only
#define KTILE(CB, NB, KT)                                                   \
  {                                                                         \
    const char* An = Ab + (((KT) + 1) & (NKT - 1)) * BKB;                   \
    const char* Bn = Bb + (((KT) + 1) & (NKT - 1)) * BKB;                   \
    _Pragma("unroll") for (int c = 0; c < 4; ++c)                           \
      gload16(An + soff[c], (NB) + loff[c]);                                \
    _Pragma("unroll") for (int c = 0; c < 4; ++c)                           \
      gload16(Bn + soff[c], (NB) + 32768 + loff[c]);                        \
    RD_A(aX, CB, 0, co0);                                                   \
    RD_B(bX, (CB) + 32768, co0);                                            \
    RD_A(aY, CB, 1, co0);                                                   \
    MM(0, aX, bX);                                                          \
    RD_B(bY, (CB) + 32768, co1);                                            \
    MM(1, aY, bX);                                                          \
    RD_A(aX, CB, 0, co1);                                                   \
    MM(0, aX, bY);                                                          \
    RD_A(aY, CB, 1, co1);                                                   \
    MM(1, aY, bY);                                                          \
    asm volatile("s_waitcnt vmcnt(0)" ::: "memory");                        \
    __builtin_amdgcn_s_barrier();                                           \
  }

__global__ __launch_bounds__(512, 1) void k_gemm(
    const char* __restrict__ xq, const char* __restrict__ wq,
    const float* __restrict__ ascale, const double* __restrict__ wsd,
    float* __restrict__ out) {
  __shared__ __align__(16) char lds[131072];   // 2 bufs x (A 32K | B 32K)
  char* buf0 = lds;
  char* buf1 = lds + 65536;

  const int tid = threadIdx.x;
  const int l = tid & 63;
  const int wv = tid >> 6;        // 0..7
  const int wm = wv >> 2;         // M half
  const int wn = wv & 3;          // N quarter
  const int g = l >> 4, r16 = l & 15;

  // XCD-aware bijective swizzle: 512 blocks = 8 xcd * 64 chunk
  const int bid = blockIdx.x;
  const int logical = (bid & 7) * 64 + (bid >> 3);
  const int br = logical >> 3;    // 0..63  (M blocks)
  const int bc = logical & 7;     // 0..7   (N blocks)

  const char* Ab = xq + (size_t)br * 256 * K_DIM;
  const char* Bb = wq + (size_t)bc * 256 * K_DIM;

  // staging: operand tile = 256 rows x 128 B = 32 KB = 4 chunks (512 thr x 16 B)
  // LDS dest linear (global_load_lds constraint), source pre-swizzled with the
  // proven involution byte ^= (row&7)<<4 (128 B rows, 0 conflicts R2-R9)
  int soff[4], loff[4];
#pragma unroll
  for (int c = 0; c < 4; ++c) {
    int lb = c * 8192 + tid * 16;
    loff[c] = lb;
    int row = lb >> 7;
    int cb = lb & 127;
    soff[c] = row * K_DIM + (cb ^ ((row & 7) << 4));
  }

  // read-side swizzled column offsets (row&7 == r16&7 for all fragment rows)
  const int sw = (r16 & 7) << 4;
  const int co0 = (g * 16) ^ sw;        // k-slice 0
  const int co1 = (64 + g * 16) ^ sw;   // k-slice 1
  const int rA = wm * 128 + r16;
  const int rB = wn * 64 + r16;

  int4v acc[8][4];
#pragma unroll
  for (int mf = 0; mf < 8; ++mf)
#pragma unroll
    for (int nf = 0; nf < 4; ++nf) acc[mf][nf] = (int4v){0, 0, 0, 0};

  // prologue: stage tile 0 into buf0, drain, sync
#pragma unroll
  for (int c = 0; c < 4; ++c) gload16(Ab + soff[c], buf0 + loff[c]);
#pragma unroll
  for (int c = 0; c < 4; ++c) gload16(Bb + soff[c], buf0 + 32768 + loff[c]);
  asm volatile("s_waitcnt vmcnt(0)" ::: "memory");
  __builtin_amdgcn_s_barrier();

  int4v aX[4], aY[4], bX[4], bY[4];

  for (int kt = 0; kt < NKT; kt += 2) {
    KTILE(buf0, buf1, kt);
    KTILE(buf1, buf0, kt + 1);
  }

  // epilogue: y = acc * w_scale * (a_scale[t]/127); |acc| <= 127*2048 < 2^24 exact
  float wsf = (float)(*wsd);
  size_t trow0 = (size_t)br * 256 + wm * 128;
  int oc0 = bc * 256 + wn * 64;
#pragma unroll
  for (int mf = 0; mf < 8; ++mf) {
#pragma unroll
    for (int j = 0; j < 4; ++j) {
      size_t t = trow0 + mf * 16 + g * 4 + j;  // C/D: col=lane&15, row=(lane>>4)*4+reg
      float s = wsf * (ascale[t] / 127.0f);
      float* yr = out + t * (size_t)N_DIM + oc0;
#pragma unroll
      for (int nf = 0; nf < 4; ++nf) yr[nf * 16 + r16] = (float)acc[mf][nf][j] * s;
    }
  }
}

extern "C" void kernel_launch(void* const* d_in, const int* in_sizes, int n_in,
                              void* d_out, int out_size, void* d_ws, size_t ws_size,
                              hipStream_t stream) {
  const float* x = (const float*)d_in[0];
  const float* w = (const float*)d_in[1];
  float* out = (float*)d_out;

  char* ws = (char*)d_ws;
  double* red = (double*)ws;                               // 256 * 8 B
  double* wsd = (double*)(ws + 2048);                      // 1 double
  float* ascale = (float*)(ws + 4096);                     // 16384 floats
  char* xq = (char*)(ws + 4096 + 65536);                   // 32 MiB
  char* wq = xq + (size_t)M_DIM * K_DIM;                   // 4 MiB

  k_xquant<<<M_DIM, 256, 0, stream>>>(x, ascale, xq, (const float4*)w, red);
  k_wquant<<<NW / 4 / 256, 256, 0, stream>>>((const float4*)w, red, wsd, (char4*)wq);
  k_gemm<<<dim3(N_DIM / 256 * M_DIM / 256), 512, 0, stream>>>(xq, wq, ascale, wsd, out);
}